// Round 6
// baseline (1251.501 us; speedup 1.0000x reference)
//
#include <hip/hip_runtime.h>
#include <hip/hip_bf16.h>
#include <stdint.h>

#define N_NODES 100000
constexpr float BN_EPS = 1e-5f;

typedef __bf16 bf16x8 __attribute__((ext_vector_type(8)));
typedef float f32x4 __attribute__((ext_vector_type(4)));

// bucket = dst >> 9  (512 nodes per bucket)
#define BSHIFT 9
#define NBUCK ((N_NODES + 511) >> 9)   // 196

// ---------------- prep: self-detect dtype + convert + degree count ---------
// int64 detection: odd 32-bit words of the first 64 edges are the high halves
// (always 0 since idx < 1e5). For int32 they are random indices; all-zero
// probability ~1e-320.
__global__ void k_prep(const unsigned int* __restrict__ w, int E,
                       int* __restrict__ idx32, int* __restrict__ deg) {
    unsigned int wv = w[1 + 2 * (threadIdx.x & 63)];
    int f = __any(wv != 0);            // 1 => int32, 0 => int64
    int e = blockIdx.x * blockDim.x + threadIdx.x;
    if (e >= E) return;
    int s = (int)(f ? w[e] : w[2 * (size_t)e]);
    int d = (int)(f ? w[E + e] : w[2 * ((size_t)E + e)]);
    idx32[e] = s;
    idx32[E + e] = d;
    atomicAdd(&deg[d], 1);
}

// ---------------- scan1 (+ fused weight prep in extra blocks) ----------------
__global__ __launch_bounds__(256) void k_scan1(const int* __restrict__ deg,
                                               int* __restrict__ offs,
                                               int* __restrict__ bsum, int n,
                                               int nbScan,
                                               const float* __restrict__ W1l,
                                               const float* __restrict__ W1r,
                                               const float* __restrict__ W2l,
                                               const float* __restrict__ W2r,
                                               __bf16* __restrict__ Wt1hi,
                                               __bf16* __restrict__ Wt1lo,
                                               __bf16* __restrict__ Wt2hi,
                                               __bf16* __restrict__ Wt2lo) {
    if ((int)blockIdx.x >= nbScan) {
        // weight prep: Wt[c][k] (transposed, hi/lo split), K=128 both layers
        int idx = (blockIdx.x - nbScan) * 256 + threadIdx.x;
        const float* W; __bf16 *Whi, *Wlo; int halfN, lidx;
        if (idx < 2 * 128 * 128) {           // layer 1: halfN=128
            lidx = idx; halfN = 128; Whi = Wt1hi; Wlo = Wt1lo;
            int c = lidx >> 7;
            W = (c < 128) ? W1l : W1r;
        } else {                              // layer 2: halfN=64
            lidx = idx - 2 * 128 * 128;
            if (lidx >= 2 * 64 * 128) return;
            halfN = 64; Whi = Wt2hi; Wlo = Wt2lo;
            int c = lidx >> 7;
            W = (c < 64) ? W2l : W2r;
        }
        int c = lidx >> 7, k = lidx & 127;
        int cc = (c < halfN) ? c : c - halfN;
        float v = W[(size_t)k * halfN + cc];
        __bf16 h = (__bf16)v;
        Whi[lidx] = h;
        Wlo[lidx] = (__bf16)(v - (float)h);
        return;
    }
    __shared__ int s[256];
    int t = threadIdx.x;
    int i = blockIdx.x * 256 + t;
    int v = (i < n) ? deg[i] : 0;
    s[t] = v;
    __syncthreads();
    for (int off = 1; off < 256; off <<= 1) {
        int add = (t >= off) ? s[t - off] : 0;
        __syncthreads();
        s[t] += add;
        __syncthreads();
    }
    if (i < n) offs[i] = s[t] - v;
    if (t == 255) bsum[blockIdx.x] = s[255];
}

__global__ __launch_bounds__(256) void k_scan2(int* __restrict__ bsum, int nb) {
    __shared__ int s[256];
    __shared__ int carry;
    int t = threadIdx.x;
    if (t == 0) carry = 0;
    __syncthreads();
    for (int base = 0; base < nb; base += 256) {
        int i = base + t;
        int v = (i < nb) ? bsum[i] : 0;
        s[t] = v;
        __syncthreads();
        for (int off = 1; off < 256; off <<= 1) {
            int add = (t >= off) ? s[t - off] : 0;
            __syncthreads();
            s[t] += add;
            __syncthreads();
        }
        if (i < nb) bsum[i] = s[t] - v + carry;
        __syncthreads();
        if (t == 0) carry += s[255];
        __syncthreads();
    }
}

// scan3: finalize offs, and init bucket frontier counters = offs[b*512]
__global__ void k_scan3(int* __restrict__ offs, const int* __restrict__ bsum,
                        int n, int E, int* __restrict__ bucketFill) {
    int i = blockIdx.x * blockDim.x + threadIdx.x;
    if (i < n) {
        int val = offs[i] + bsum[i >> 8];
        offs[i] = val;
        if ((i & 511) == 0) bucketFill[i >> BSHIFT] = val;
    }
    if (i == 0) offs[n] = E;
}

// ---------------- bf16x3 MFMA GEMM body (device) ------------
template <int K, int NCS, int SPLITC>
__device__ void mfma_body(const float* __restrict__ A,
                          const __bf16* __restrict__ Wthi,
                          const __bf16* __restrict__ Wtlo,
                          __bf16* __restrict__ Cl, float* __restrict__ Cr,
                          int M, int bid) {
    const int lane = threadIdx.x & 63;
    const int wave = threadIdx.x >> 6;
    const int row0 = bid * 128 + wave * 32;
    const int rlo = lane & 15;
    const int rhi = lane >> 4;            // 0..3

    f32x4 acc[NCS][2][2] = {};

    for (int k0 = 0; k0 < K; k0 += 32) {
        bf16x8 ahi[2], alo[2];
        #pragma unroll
        for (int wr = 0; wr < 2; ++wr) {
            int row = row0 + wr * 16 + rlo;
            row = row < M ? row : M - 1;
            const float* ap = A + (size_t)row * K + k0 + rhi * 8;
            float4 v0 = *(const float4*)ap;
            float4 v1 = *(const float4*)(ap + 4);
            float vv[8] = {v0.x, v0.y, v0.z, v0.w, v1.x, v1.y, v1.z, v1.w};
            #pragma unroll
            for (int i = 0; i < 8; ++i) {
                __bf16 h = (__bf16)vv[i];
                ahi[wr][i] = h;
                alo[wr][i] = (__bf16)(vv[i] - (float)h);
            }
        }
        #pragma unroll
        for (int cs = 0; cs < NCS; ++cs) {
            #pragma unroll
            for (int cf = 0; cf < 2; ++cf) {
                int c = cs * 32 + cf * 16 + rlo;
                size_t boff = (size_t)c * K + k0 + rhi * 8;
                bf16x8 bhi = *(const bf16x8*)(Wthi + boff);
                bf16x8 blo = *(const bf16x8*)(Wtlo + boff);
                #pragma unroll
                for (int wr = 0; wr < 2; ++wr) {
                    f32x4 a = acc[cs][wr][cf];
                    a = __builtin_amdgcn_mfma_f32_16x16x32_bf16(ahi[wr], bhi, a, 0, 0, 0);
                    a = __builtin_amdgcn_mfma_f32_16x16x32_bf16(ahi[wr], blo, a, 0, 0, 0);
                    a = __builtin_amdgcn_mfma_f32_16x16x32_bf16(alo[wr], bhi, a, 0, 0, 0);
                    acc[cs][wr][cf] = a;
                }
            }
        }
    }

    #pragma unroll
    for (int cs = 0; cs < NCS; ++cs)
        #pragma unroll
        for (int cf = 0; cf < 2; ++cf) {
            int c = cs * 32 + cf * 16 + rlo;
            #pragma unroll
            for (int wr = 0; wr < 2; ++wr)
                #pragma unroll
                for (int r = 0; r < 4; ++r) {
                    int row = row0 + wr * 16 + rhi * 4 + r;
                    if (row < M) {
                        float val = acc[cs][wr][cf][r];
                        if (c < SPLITC)
                            Cl[(size_t)row * SPLITC + c] = (__bf16)val;
                        else
                            Cr[(size_t)row * (NCS * 32 - SPLITC) + (c - SPLITC)] = val;
                    }
                }
        }
}

// plain GEMM kernel (layer 2)
template <int K, int NCS, int SPLITC>
__global__ __launch_bounds__(256) void k_mfma(const float* __restrict__ A,
                                              const __bf16* __restrict__ Wthi,
                                              const __bf16* __restrict__ Wtlo,
                                              __bf16* __restrict__ Cl,
                                              float* __restrict__ Cr, int M) {
    mfma_body<K, NCS, SPLITC>(A, Wthi, Wtlo, Cl, Cr, M, blockIdx.x);
}

// fused bucket-append (FIRST: short blocks flood & drain) + GEMM
template <int K, int NCS, int SPLITC>
__global__ __launch_bounds__(256) void k_mfma_bin(const float* __restrict__ A,
                                                  const __bf16* __restrict__ Wthi,
                                                  const __bf16* __restrict__ Wtlo,
                                                  __bf16* __restrict__ Cl,
                                                  float* __restrict__ Cr, int M,
                                                  int binBlocks,
                                                  const int* __restrict__ idx32,
                                                  int* __restrict__ bucketFill,
                                                  unsigned int* __restrict__ ebuf,
                                                  int E) {
    if ((int)blockIdx.x < binBlocks) {
        int e = blockIdx.x * 256 + threadIdx.x;
        if (e < E) {
            int s = idx32[e];
            int d = idx32[E + e];
            int pos = atomicAdd(&bucketFill[d >> BSHIFT], 1);
            ebuf[pos] = (unsigned int)s | ((unsigned int)(d & 511) << 17);
        }
        return;
    }
    mfma_body<K, NCS, SPLITC>(A, Wthi, Wtlo, Cl, Cr, M, blockIdx.x - binBlocks);
}

// ---------------- per-bucket LDS counting sort -> csr ----------------------
__global__ __launch_bounds__(256) void k_csrbuild(const unsigned int* __restrict__ ebuf,
                                                  const int* __restrict__ offs,
                                                  int* __restrict__ csr, int N) {
    __shared__ int lfill[512];
    __shared__ int stage[16384];     // 64 KB
    int b = blockIdx.x;
    int n0 = b << BSHIFT;
    int n1 = min(n0 + 512, N);
    int base = offs[n0];
    int cnt = offs[n1] - base;
    for (int i = threadIdx.x; i < 512; i += 256)
        lfill[i] = (n0 + i < n1) ? offs[n0 + i] - base : cnt;
    __syncthreads();
    if (cnt <= 16384) {
        for (int t = threadIdx.x; t < cnt; t += 256) {
            unsigned int p = ebuf[base + t];
            int lpos = atomicAdd(&lfill[p >> 17], 1);
            stage[lpos] = (int)(p & 0x1ffff);
        }
        __syncthreads();
        for (int t = threadIdx.x; t < cnt; t += 256)
            csr[base + t] = stage[t];
    } else {   // overflow fallback (never for uniform graphs)
        for (int t = threadIdx.x; t < cnt; t += 256) {
            unsigned int p = ebuf[base + t];
            int lpos = atomicAdd(&lfill[p >> 17], 1);
            csr[base + lpos] = (int)(p & 0x1ffff);
        }
    }
}

// ---------------- fused gather(bf16) + mean + lin_r + BN + ReLU ------------
template <int LOGF>
__global__ __launch_bounds__(256) void k_agg(const __bf16* __restrict__ xl,
                                             const float* __restrict__ lin,
                                             const int* __restrict__ csr,
                                             const int* __restrict__ offs,
                                             const float* __restrict__ b,
                                             const float* __restrict__ g,
                                             const float* __restrict__ be,
                                             const float* __restrict__ m,
                                             const float* __restrict__ v,
                                             float* __restrict__ out, int N) {
    constexpr int F = 1 << LOGF;
    int node = blockIdx.x * 4 + (threadIdx.x >> 6);
    if (node >= N) return;
    int lane = threadIdx.x & 63;
    int beg = offs[node], end = offs[node + 1];
    float inv = 1.0f / fmaxf((float)(end - beg), 1.0f);

    if constexpr (F == 128) {
        float sx = 0.f, sy = 0.f;
        const unsigned int* base = (const unsigned int*)xl;
        int e = beg;
        while (e < end) {
            int bl = min(64, end - e);
            int myidx = (lane < bl) ? csr[e + lane] : 0;
            int u = 0;
            for (; u + 8 <= bl; u += 8) {
                unsigned int t[8];
                #pragma unroll
                for (int i = 0; i < 8; ++i) {
                    int sidx = __shfl(myidx, u + i, 64);
                    t[i] = base[(size_t)sidx * 64 + lane];
                }
                #pragma unroll
                for (int i = 0; i < 8; ++i) {
                    sx += __uint_as_float(t[i] << 16);
                    sy += __uint_as_float(t[i] & 0xffff0000u);
                }
            }
            for (; u < bl; ++u) {
                int sidx = __shfl(myidx, u, 64);
                unsigned int t = base[(size_t)sidx * 64 + lane];
                sx += __uint_as_float(t << 16);
                sy += __uint_as_float(t & 0xffff0000u);
            }
            e += bl;
        }
        int f0 = lane * 2;
        size_t o = (size_t)node * 128 + f0;
        float2 l2 = *(const float2*)(lin + o);
        float y0 = ((sx * inv + b[f0]     + l2.x) - m[f0])     * (g[f0]     * rsqrtf(v[f0]     + BN_EPS)) + be[f0];
        float y1 = ((sy * inv + b[f0 + 1] + l2.y) - m[f0 + 1]) * (g[f0 + 1] * rsqrtf(v[f0 + 1] + BN_EPS)) + be[f0 + 1];
        *(float2*)(out + o) = make_float2(fmaxf(y0, 0.f), fmaxf(y1, 0.f));
    } else {
        float s = 0.f;
        const unsigned short* base = (const unsigned short*)xl;
        int e = beg;
        while (e < end) {
            int bl = min(64, end - e);
            int myidx = (lane < bl) ? csr[e + lane] : 0;
            int u = 0;
            for (; u + 8 <= bl; u += 8) {
                unsigned int t[8];
                #pragma unroll
                for (int i = 0; i < 8; ++i) {
                    int sidx = __shfl(myidx, u + i, 64);
                    t[i] = base[(size_t)sidx * 64 + lane];
                }
                #pragma unroll
                for (int i = 0; i < 8; ++i)
                    s += __uint_as_float(t[i] << 16);
            }
            for (; u < bl; ++u) {
                int sidx = __shfl(myidx, u, 64);
                s += __uint_as_float((unsigned int)base[(size_t)sidx * 64 + lane] << 16);
            }
            e += bl;
        }
        size_t o = (size_t)node * 64 + lane;
        float y = ((s * inv + b[lane] + lin[o]) - m[lane]) * (g[lane] * rsqrtf(v[lane] + BN_EPS)) + be[lane];
        out[o] = fmaxf(y, 0.f);
    }
}

// ---------------- head: out[M,10] = h2[M,64] @ Wh[64,10] + bh --------------
__global__ __launch_bounds__(256) void k_head(const float* __restrict__ h2,
                                              const float* __restrict__ Wh,
                                              const float* __restrict__ bh,
                                              float* __restrict__ out, int M) {
    __shared__ float sW[64 * 10];
    __shared__ float sb[10];
    for (int i = threadIdx.x; i < 640; i += 256) sW[i] = Wh[i];
    if (threadIdx.x < 10) sb[threadIdx.x] = bh[threadIdx.x];
    __syncthreads();
    int n = blockIdx.x * blockDim.x + threadIdx.x;
    if (n >= M) return;
    float acc[10];
    #pragma unroll
    for (int c = 0; c < 10; ++c) acc[c] = sb[c];
    const float* hr = h2 + (size_t)n * 64;
    #pragma unroll
    for (int k = 0; k < 64; ++k) {
        float hv = hr[k];
        #pragma unroll
        for (int c = 0; c < 10; ++c) acc[c] = fmaf(hv, sW[k * 10 + c], acc[c]);
    }
    #pragma unroll
    for (int c = 0; c < 10; ++c) out[(size_t)n * 10 + c] = acc[c];
}

// ---------------------------------------------------------------------------
static inline size_t align256(size_t x) { return (x + 255) & ~(size_t)255; }

extern "C" void kernel_launch(void* const* d_in, const int* in_sizes, int n_in,
                              void* d_out, int out_size, void* d_ws, size_t ws_size,
                              hipStream_t stream) {
    const float* x   = (const float*)d_in[0];
    const void*  ei  = d_in[1];
    const float* W1l = (const float*)d_in[2];
    const float* b1l = (const float*)d_in[3];
    const float* W1r = (const float*)d_in[4];
    const float* g1  = (const float*)d_in[5];
    const float* be1 = (const float*)d_in[6];
    const float* m1  = (const float*)d_in[7];
    const float* v1  = (const float*)d_in[8];
    const float* W2l = (const float*)d_in[9];
    const float* b2l = (const float*)d_in[10];
    const float* W2r = (const float*)d_in[11];
    const float* g2  = (const float*)d_in[12];
    const float* be2 = (const float*)d_in[13];
    const float* m2  = (const float*)d_in[14];
    const float* v2  = (const float*)d_in[15];
    const float* Wh  = (const float*)d_in[16];
    const float* bh  = (const float*)d_in[17];
    float* out = (float*)d_out;

    const int N = N_NODES;
    const int E = in_sizes[1] / 2;
    const int NB = (N + 255) / 256;

    // -------- workspace layout --------
    char* p = (char*)d_ws;
    int* idx32 = (int*)p;  p += align256((size_t)2 * E * 4);
    unsigned int* ebuf = (unsigned int*)p; p += align256((size_t)E * 4);
    int* csr   = (int*)p;  p += align256((size_t)E * 4);
    int* offs  = (int*)p;  p += align256((size_t)(N + 1) * 4);
    int* deg   = (int*)p;  p += align256((size_t)N * 4);
    int* bucketFill = (int*)p; p += align256((size_t)NBUCK * 4);
    int* bsum  = (int*)p;  p += 4096;
    __bf16* Wt1hi = (__bf16*)p; p += align256((size_t)256 * 128 * 2);
    __bf16* Wt1lo = (__bf16*)p; p += align256((size_t)256 * 128 * 2);
    __bf16* Wt2hi = (__bf16*)p; p += align256((size_t)128 * 128 * 2);
    __bf16* Wt2lo = (__bf16*)p; p += align256((size_t)128 * 128 * 2);
    __bf16* xl = (__bf16*)p; p += align256((size_t)N * 128 * 2);
    float* xr  = (float*)p;  p += (size_t)N * 128 * 4;
    float* h   = (float*)p;  p += (size_t)N * 128 * 4;
    // layer-2 reuse
    __bf16* t2l = xl;                    // [N,64] bf16
    float* t2r  = xr;                    // [N,64] f32
    float* h2   = h;                     // [N,64] f32 (h dead after mfma2)

    dim3 blk(256);

    // -------- edge prep: self-detect + convert + degree --------
    hipMemsetAsync(deg, 0, (size_t)N * 4, stream);
    k_prep<<<dim3((E + 255) / 256), blk, 0, stream>>>(
        (const unsigned int*)ei, E, idx32, deg);

    // -------- scans (+ fused weight prep) --------
    const int WPB = (2 * 128 * 128 + 2 * 64 * 128 + 255) / 256;   // 192
    k_scan1<<<dim3(NB + WPB), blk, 0, stream>>>(deg, offs, bsum, N, NB,
        W1l, W1r, W2l, W2r, Wt1hi, Wt1lo, Wt2hi, Wt2lo);
    k_scan2<<<dim3(1), blk, 0, stream>>>(bsum, NB);
    k_scan3<<<dim3(NB), blk, 0, stream>>>(offs, bsum, N, E, bucketFill);

    // -------- bucket append (first) co-scheduled with layer-1 GEMM --------
    int gemmBlocks = (N + 127) / 128;
    int binBlocks = (E + 255) / 256;
    k_mfma_bin<128, 8, 128><<<dim3(binBlocks + gemmBlocks), blk, 0, stream>>>(
        x, Wt1hi, Wt1lo, xl, xr, N, binBlocks, idx32, bucketFill, ebuf, E);

    // -------- per-bucket counting sort -> csr --------
    k_csrbuild<<<dim3(NBUCK), blk, 0, stream>>>(ebuf, offs, csr, N);

    // -------- layer 1 aggregate --------
    k_agg<7><<<dim3((N + 3) / 4), blk, 0, stream>>>(
        xl, xr, csr, offs, b1l, g1, be1, m1, v1, h, N);

    // -------- layer 2 --------
    k_mfma<128, 4, 64><<<dim3(gemmBlocks), blk, 0, stream>>>(h, Wt2hi, Wt2lo, t2l, t2r, N);
    k_agg<6><<<dim3((N + 3) / 4), blk, 0, stream>>>(
        t2l, t2r, csr, offs, b2l, g2, be2, m2, v2, h2, N);

    // -------- head --------
    k_head<<<dim3((N + 255) / 256), blk, 0, stream>>>(h2, Wh, bh, out, N);
}

// Round 7
// 430.502 us; speedup vs baseline: 2.9071x; 2.9071x over previous
//
#include <hip/hip_runtime.h>
#include <hip/hip_bf16.h>
#include <stdint.h>

#define N_NODES 100000
constexpr float BN_EPS = 1e-5f;

typedef __bf16 bf16x8 __attribute__((ext_vector_type(8)));
typedef float f32x4 __attribute__((ext_vector_type(4)));

// ---------------- fused weight-prep + edge prep ----------------
// blocks [0,wpB): split fp32 W -> bf16 hi/lo transposed Wt[c][k]
// blocks [wpB,...): self-detect ei dtype, convert to int32, rank = deg[d]++
__global__ __launch_bounds__(256) void k_prep(const unsigned int* __restrict__ w, int E,
                                              int* __restrict__ idx32,
                                              int* __restrict__ rank,
                                              int* __restrict__ deg, int wpB,
                                              const float* __restrict__ W1l,
                                              const float* __restrict__ W1r,
                                              const float* __restrict__ W2l,
                                              const float* __restrict__ W2r,
                                              __bf16* __restrict__ Wt1hi,
                                              __bf16* __restrict__ Wt1lo,
                                              __bf16* __restrict__ Wt2hi,
                                              __bf16* __restrict__ Wt2lo) {
    if ((int)blockIdx.x < wpB) {
        int idx = blockIdx.x * 256 + threadIdx.x;
        const float* W; __bf16 *Whi, *Wlo; int halfN, lidx;
        if (idx < 2 * 128 * 128) {
            lidx = idx; halfN = 128; Whi = Wt1hi; Wlo = Wt1lo;
            W = ((lidx >> 7) < 128) ? W1l : W1r;
        } else {
            lidx = idx - 2 * 128 * 128;
            if (lidx >= 2 * 64 * 128) return;
            halfN = 64; Whi = Wt2hi; Wlo = Wt2lo;
            W = ((lidx >> 7) < 64) ? W2l : W2r;
        }
        int c = lidx >> 7, k = lidx & 127;
        int cc = (c < halfN) ? c : c - halfN;
        float v = W[(size_t)k * halfN + cc];
        __bf16 h = (__bf16)v;
        Whi[lidx] = h;
        Wlo[lidx] = (__bf16)(v - (float)h);
        return;
    }
    // int64 detection: odd words of first 64 edges are high halves (0 for
    // int64 since idx<1e5); for int32 they're random src indices.
    unsigned int wv = w[1 + 2 * (threadIdx.x & 63)];
    int f = __any(wv != 0);            // 1 => int32, 0 => int64
    int e = (blockIdx.x - wpB) * 256 + threadIdx.x;
    if (e >= E) return;
    int s = (int)(f ? w[e] : w[2 * (size_t)e]);
    int d = (int)(f ? w[E + e] : w[2 * ((size_t)E + e)]);
    idx32[e] = s;
    idx32[E + e] = d;
    rank[e] = atomicAdd(&deg[d], 1);
}

// ---------------- scans ----------------
__global__ __launch_bounds__(256) void k_scan1(const int* __restrict__ deg,
                                               int* __restrict__ offs,
                                               int* __restrict__ bsum, int n) {
    __shared__ int s[256];
    int t = threadIdx.x;
    int i = blockIdx.x * 256 + t;
    int v = (i < n) ? deg[i] : 0;
    s[t] = v;
    __syncthreads();
    for (int off = 1; off < 256; off <<= 1) {
        int add = (t >= off) ? s[t - off] : 0;
        __syncthreads();
        s[t] += add;
        __syncthreads();
    }
    if (i < n) offs[i] = s[t] - v;
    if (t == 255) bsum[blockIdx.x] = s[255];
}

__global__ __launch_bounds__(256) void k_scan2(int* __restrict__ bsum, int nb) {
    __shared__ int s[256];
    __shared__ int carry;
    int t = threadIdx.x;
    if (t == 0) carry = 0;
    __syncthreads();
    for (int base = 0; base < nb; base += 256) {
        int i = base + t;
        int v = (i < nb) ? bsum[i] : 0;
        s[t] = v;
        __syncthreads();
        for (int off = 1; off < 256; off <<= 1) {
            int add = (t >= off) ? s[t - off] : 0;
            __syncthreads();
            s[t] += add;
            __syncthreads();
        }
        if (i < nb) bsum[i] = s[t] - v + carry;
        __syncthreads();
        if (t == 0) carry += s[255];
        __syncthreads();
    }
}

__global__ void k_scan3(int* __restrict__ offs, const int* __restrict__ bsum,
                        int n, int E) {
    int i = blockIdx.x * blockDim.x + threadIdx.x;
    if (i < n) offs[i] += bsum[i >> 8];
    if (i == 0) offs[n] = E;
}

// ---------------- bf16x3 MFMA GEMM body (device) ------------
template <int K, int NCS, int SPLITC>
__device__ void mfma_body(const float* __restrict__ A,
                          const __bf16* __restrict__ Wthi,
                          const __bf16* __restrict__ Wtlo,
                          __bf16* __restrict__ Cl, float* __restrict__ Cr,
                          int M, int bid) {
    const int lane = threadIdx.x & 63;
    const int wave = threadIdx.x >> 6;
    const int row0 = bid * 128 + wave * 32;
    const int rlo = lane & 15;
    const int rhi = lane >> 4;            // 0..3

    f32x4 acc[NCS][2][2] = {};

    for (int k0 = 0; k0 < K; k0 += 32) {
        bf16x8 ahi[2], alo[2];
        #pragma unroll
        for (int wr = 0; wr < 2; ++wr) {
            int row = row0 + wr * 16 + rlo;
            row = row < M ? row : M - 1;
            const float* ap = A + (size_t)row * K + k0 + rhi * 8;
            float4 v0 = *(const float4*)ap;
            float4 v1 = *(const float4*)(ap + 4);
            float vv[8] = {v0.x, v0.y, v0.z, v0.w, v1.x, v1.y, v1.z, v1.w};
            #pragma unroll
            for (int i = 0; i < 8; ++i) {
                __bf16 h = (__bf16)vv[i];
                ahi[wr][i] = h;
                alo[wr][i] = (__bf16)(vv[i] - (float)h);
            }
        }
        #pragma unroll
        for (int cs = 0; cs < NCS; ++cs) {
            #pragma unroll
            for (int cf = 0; cf < 2; ++cf) {
                int c = cs * 32 + cf * 16 + rlo;
                size_t boff = (size_t)c * K + k0 + rhi * 8;
                bf16x8 bhi = *(const bf16x8*)(Wthi + boff);
                bf16x8 blo = *(const bf16x8*)(Wtlo + boff);
                #pragma unroll
                for (int wr = 0; wr < 2; ++wr) {
                    f32x4 a = acc[cs][wr][cf];
                    a = __builtin_amdgcn_mfma_f32_16x16x32_bf16(ahi[wr], bhi, a, 0, 0, 0);
                    a = __builtin_amdgcn_mfma_f32_16x16x32_bf16(ahi[wr], blo, a, 0, 0, 0);
                    a = __builtin_amdgcn_mfma_f32_16x16x32_bf16(alo[wr], bhi, a, 0, 0, 0);
                    acc[cs][wr][cf] = a;
                }
            }
        }
    }

    #pragma unroll
    for (int cs = 0; cs < NCS; ++cs)
        #pragma unroll
        for (int cf = 0; cf < 2; ++cf) {
            int c = cs * 32 + cf * 16 + rlo;
            #pragma unroll
            for (int wr = 0; wr < 2; ++wr)
                #pragma unroll
                for (int r = 0; r < 4; ++r) {
                    int row = row0 + wr * 16 + rhi * 4 + r;
                    if (row < M) {
                        float val = acc[cs][wr][cf][r];
                        if (c < SPLITC)
                            Cl[(size_t)row * SPLITC + c] = (__bf16)val;
                        else
                            Cr[(size_t)row * (NCS * 32 - SPLITC) + (c - SPLITC)] = val;
                    }
                }
        }
}

// plain GEMM kernel (layer 2)
template <int K, int NCS, int SPLITC>
__global__ __launch_bounds__(256) void k_mfma(const float* __restrict__ A,
                                              const __bf16* __restrict__ Wthi,
                                              const __bf16* __restrict__ Wtlo,
                                              __bf16* __restrict__ Cl,
                                              float* __restrict__ Cr, int M) {
    mfma_body<K, NCS, SPLITC>(A, Wthi, Wtlo, Cl, Cr, M, blockIdx.x);
}

// fused CSR-scatter (FIRST: short blocks flood & drain) + layer-1 GEMM
template <int K, int NCS, int SPLITC>
__global__ __launch_bounds__(256) void k_bin_mfma(const float* __restrict__ A,
                                                  const __bf16* __restrict__ Wthi,
                                                  const __bf16* __restrict__ Wtlo,
                                                  __bf16* __restrict__ Cl,
                                                  float* __restrict__ Cr, int M,
                                                  int binBlocks,
                                                  const int* __restrict__ idx32,
                                                  const int* __restrict__ rank,
                                                  const int* __restrict__ offs,
                                                  int* __restrict__ csr, int E) {
    if ((int)blockIdx.x < binBlocks) {
        int e = blockIdx.x * 256 + threadIdx.x;
        if (e < E) {
            int d = idx32[E + e];
            csr[offs[d] + rank[e]] = idx32[e];
        }
        return;
    }
    mfma_body<K, NCS, SPLITC>(A, Wthi, Wtlo, Cl, Cr, M, blockIdx.x - binBlocks);
}

// ---------------- fused gather(bf16) + mean + lin_r + BN + ReLU ------------
// TWO waves per node (contiguous half-split, LDS combine) for 2x latency hiding
template <int LOGF>
__global__ __launch_bounds__(256) void k_agg(const __bf16* __restrict__ xl,
                                             const float* __restrict__ lin,
                                             const int* __restrict__ csr,
                                             const int* __restrict__ offs,
                                             const float* __restrict__ b,
                                             const float* __restrict__ g,
                                             const float* __restrict__ be,
                                             const float* __restrict__ m,
                                             const float* __restrict__ v,
                                             float* __restrict__ out, int N) {
    constexpr int F = 1 << LOGF;
    __shared__ float spart[2][128];
    int nsub = threadIdx.x >> 7;          // node slot within block (0/1)
    int node = blockIdx.x * 2 + nsub;
    int wsub = (threadIdx.x >> 6) & 1;    // which wave of the pair
    int lane = threadIdx.x & 63;

    int beg = 0, end = 0;
    if (node < N) { beg = offs[node]; end = offs[node + 1]; }
    int cnt = end - beg;
    int mid = beg + ((cnt + 1) >> 1);
    int lo = wsub ? mid : beg;
    int hi = wsub ? end : mid;

    if constexpr (F == 128) {
        float sx = 0.f, sy = 0.f;
        const unsigned int* base = (const unsigned int*)xl;
        int e = lo;
        while (e < hi) {
            int bl = min(64, hi - e);
            int myidx = (lane < bl) ? csr[e + lane] : 0;
            int u = 0;
            for (; u + 8 <= bl; u += 8) {
                unsigned int t[8];
                #pragma unroll
                for (int i = 0; i < 8; ++i) {
                    int sidx = __shfl(myidx, u + i, 64);
                    t[i] = base[(size_t)sidx * 64 + lane];
                }
                #pragma unroll
                for (int i = 0; i < 8; ++i) {
                    sx += __uint_as_float(t[i] << 16);
                    sy += __uint_as_float(t[i] & 0xffff0000u);
                }
            }
            for (; u < bl; ++u) {
                int sidx = __shfl(myidx, u, 64);
                unsigned int t = base[(size_t)sidx * 64 + lane];
                sx += __uint_as_float(t << 16);
                sy += __uint_as_float(t & 0xffff0000u);
            }
            e += bl;
        }
        if (wsub) {
            spart[nsub][lane * 2] = sx;
            spart[nsub][lane * 2 + 1] = sy;
        }
        __syncthreads();
        if (!wsub && node < N) {
            sx += spart[nsub][lane * 2];
            sy += spart[nsub][lane * 2 + 1];
            float inv = 1.0f / fmaxf((float)cnt, 1.0f);
            int f0 = lane * 2;
            size_t o = (size_t)node * 128 + f0;
            float2 l2 = *(const float2*)(lin + o);
            float y0 = ((sx * inv + b[f0]     + l2.x) - m[f0])     * (g[f0]     * rsqrtf(v[f0]     + BN_EPS)) + be[f0];
            float y1 = ((sy * inv + b[f0 + 1] + l2.y) - m[f0 + 1]) * (g[f0 + 1] * rsqrtf(v[f0 + 1] + BN_EPS)) + be[f0 + 1];
            *(float2*)(out + o) = make_float2(fmaxf(y0, 0.f), fmaxf(y1, 0.f));
        }
    } else {
        float s = 0.f;
        const unsigned short* base = (const unsigned short*)xl;
        int e = lo;
        while (e < hi) {
            int bl = min(64, hi - e);
            int myidx = (lane < bl) ? csr[e + lane] : 0;
            int u = 0;
            for (; u + 8 <= bl; u += 8) {
                unsigned int t[8];
                #pragma unroll
                for (int i = 0; i < 8; ++i) {
                    int sidx = __shfl(myidx, u + i, 64);
                    t[i] = base[(size_t)sidx * 64 + lane];
                }
                #pragma unroll
                for (int i = 0; i < 8; ++i)
                    s += __uint_as_float(t[i] << 16);
            }
            for (; u < bl; ++u) {
                int sidx = __shfl(myidx, u, 64);
                s += __uint_as_float((unsigned int)base[(size_t)sidx * 64 + lane] << 16);
            }
            e += bl;
        }
        if (wsub) spart[nsub][lane] = s;
        __syncthreads();
        if (!wsub && node < N) {
            s += spart[nsub][lane];
            float inv = 1.0f / fmaxf((float)cnt, 1.0f);
            size_t o = (size_t)node * 64 + lane;
            float y = ((s * inv + b[lane] + lin[o]) - m[lane]) * (g[lane] * rsqrtf(v[lane] + BN_EPS)) + be[lane];
            out[o] = fmaxf(y, 0.f);
        }
    }
}

// ---------------- head: out[M,10] = h2[M,64] @ Wh[64,10] + bh --------------
__global__ __launch_bounds__(256) void k_head(const float* __restrict__ h2,
                                              const float* __restrict__ Wh,
                                              const float* __restrict__ bh,
                                              float* __restrict__ out, int M) {
    __shared__ float sW[64 * 10];
    __shared__ float sb[10];
    for (int i = threadIdx.x; i < 640; i += 256) sW[i] = Wh[i];
    if (threadIdx.x < 10) sb[threadIdx.x] = bh[threadIdx.x];
    __syncthreads();
    int n = blockIdx.x * blockDim.x + threadIdx.x;
    if (n >= M) return;
    float acc[10];
    #pragma unroll
    for (int c = 0; c < 10; ++c) acc[c] = sb[c];
    const float* hr = h2 + (size_t)n * 64;
    #pragma unroll
    for (int k = 0; k < 64; ++k) {
        float hv = hr[k];
        #pragma unroll
        for (int c = 0; c < 10; ++c) acc[c] = fmaf(hv, sW[k * 10 + c], acc[c]);
    }
    #pragma unroll
    for (int c = 0; c < 10; ++c) out[(size_t)n * 10 + c] = acc[c];
}

// ---------------------------------------------------------------------------
static inline size_t align256(size_t x) { return (x + 255) & ~(size_t)255; }

extern "C" void kernel_launch(void* const* d_in, const int* in_sizes, int n_in,
                              void* d_out, int out_size, void* d_ws, size_t ws_size,
                              hipStream_t stream) {
    const float* x   = (const float*)d_in[0];
    const void*  ei  = d_in[1];
    const float* W1l = (const float*)d_in[2];
    const float* b1l = (const float*)d_in[3];
    const float* W1r = (const float*)d_in[4];
    const float* g1  = (const float*)d_in[5];
    const float* be1 = (const float*)d_in[6];
    const float* m1  = (const float*)d_in[7];
    const float* v1  = (const float*)d_in[8];
    const float* W2l = (const float*)d_in[9];
    const float* b2l = (const float*)d_in[10];
    const float* W2r = (const float*)d_in[11];
    const float* g2  = (const float*)d_in[12];
    const float* be2 = (const float*)d_in[13];
    const float* m2  = (const float*)d_in[14];
    const float* v2  = (const float*)d_in[15];
    const float* Wh  = (const float*)d_in[16];
    const float* bh  = (const float*)d_in[17];
    float* out = (float*)d_out;

    const int N = N_NODES;
    const int E = in_sizes[1] / 2;
    const int NB = (N + 255) / 256;

    // -------- workspace layout --------
    char* p = (char*)d_ws;
    int* idx32 = (int*)p;  p += align256((size_t)2 * E * 4);
    int* rank  = (int*)p;  p += align256((size_t)E * 4);
    int* csr   = (int*)p;  p += align256((size_t)E * 4);
    int* offs  = (int*)p;  p += align256((size_t)(N + 1) * 4);
    int* deg   = (int*)p;  p += align256((size_t)N * 4);
    int* bsum  = (int*)p;  p += 4096;
    __bf16* Wt1hi = (__bf16*)p; p += align256((size_t)256 * 128 * 2);
    __bf16* Wt1lo = (__bf16*)p; p += align256((size_t)256 * 128 * 2);
    __bf16* Wt2hi = (__bf16*)p; p += align256((size_t)128 * 128 * 2);
    __bf16* Wt2lo = (__bf16*)p; p += align256((size_t)128 * 128 * 2);
    __bf16* xl = (__bf16*)p; p += align256((size_t)N * 128 * 2);
    float* xr  = (float*)p;  p += (size_t)N * 128 * 4;
    float* h   = (float*)p;  p += (size_t)N * 128 * 4;
    // layer-2 reuse
    __bf16* t2l = xl;                    // [N,64] bf16
    float* t2r  = xr;                    // [N,64] f32
    float* h2   = h;                     // [N,64] f32 (h dead after mfma2)

    dim3 blk(256);

    // -------- fused weight-prep + edge prep --------
    const int WPB = (2 * 128 * 128 + 2 * 64 * 128 + 255) / 256;   // 192
    int prepB = (E + 255) / 256;
    hipMemsetAsync(deg, 0, (size_t)N * 4, stream);
    k_prep<<<dim3(WPB + prepB), blk, 0, stream>>>(
        (const unsigned int*)ei, E, idx32, rank, deg, WPB,
        W1l, W1r, W2l, W2r, Wt1hi, Wt1lo, Wt2hi, Wt2lo);

    // -------- scans --------
    k_scan1<<<dim3(NB), blk, 0, stream>>>(deg, offs, bsum, N);
    k_scan2<<<dim3(1), blk, 0, stream>>>(bsum, NB);
    k_scan3<<<dim3(NB), blk, 0, stream>>>(offs, bsum, N, E);

    // -------- CSR scatter (first) co-scheduled with layer-1 GEMM --------
    int gemmBlocks = (N + 127) / 128;
    int binBlocks = (E + 255) / 256;
    k_bin_mfma<128, 8, 128><<<dim3(binBlocks + gemmBlocks), blk, 0, stream>>>(
        x, Wt1hi, Wt1lo, xl, xr, N, binBlocks, idx32, rank, offs, csr, E);

    // -------- layer 1 aggregate (2 waves/node) --------
    k_agg<7><<<dim3((N + 1) / 2), blk, 0, stream>>>(
        xl, xr, csr, offs, b1l, g1, be1, m1, v1, h, N);

    // -------- layer 2 --------
    k_mfma<128, 4, 64><<<dim3(gemmBlocks), blk, 0, stream>>>(h, Wt2hi, Wt2lo, t2l, t2r, N);
    k_agg<6><<<dim3((N + 1) / 2), blk, 0, stream>>>(
        t2l, t2r, csr, offs, b2l, g2, be2, m2, v2, h2, N);

    // -------- head --------
    k_head<<<dim3((N + 255) / 256), blk, 0, stream>>>(h2, Wh, bh, out, N);
}

// Round 8
// 352.838 us; speedup vs baseline: 3.5470x; 1.2201x over previous
//
#include <hip/hip_runtime.h>
#include <hip/hip_bf16.h>
#include <stdint.h>

#define N_NODES 100000
constexpr float BN_EPS = 1e-5f;

typedef __bf16 bf16x8 __attribute__((ext_vector_type(8)));
typedef float f32x4 __attribute__((ext_vector_type(4)));

// ---------------- fused weight-prep + edge prep ----------------
// blocks [0,wpB): split fp32 W -> bf16 hi/lo transposed Wt[c][k]
// blocks [wpB,...): self-detect ei dtype, convert to int32, rank = deg[d]++
__global__ __launch_bounds__(256) void k_prep(const unsigned int* __restrict__ w, int E,
                                              int* __restrict__ idx32,
                                              int* __restrict__ rank,
                                              int* __restrict__ deg, int wpB,
                                              const float* __restrict__ W1l,
                                              const float* __restrict__ W1r,
                                              const float* __restrict__ W2l,
                                              const float* __restrict__ W2r,
                                              __bf16* __restrict__ Wt1hi,
                                              __bf16* __restrict__ Wt1lo,
                                              __bf16* __restrict__ Wt2hi,
                                              __bf16* __restrict__ Wt2lo) {
    if ((int)blockIdx.x < wpB) {
        int idx = blockIdx.x * 256 + threadIdx.x;
        const float* W; __bf16 *Whi, *Wlo; int halfN, lidx;
        if (idx < 2 * 128 * 128) {
            lidx = idx; halfN = 128; Whi = Wt1hi; Wlo = Wt1lo;
            W = ((lidx >> 7) < 128) ? W1l : W1r;
        } else {
            lidx = idx - 2 * 128 * 128;
            if (lidx >= 2 * 64 * 128) return;
            halfN = 64; Whi = Wt2hi; Wlo = Wt2lo;
            W = ((lidx >> 7) < 64) ? W2l : W2r;
        }
        int c = lidx >> 7, k = lidx & 127;
        int cc = (c < halfN) ? c : c - halfN;
        float v = W[(size_t)k * halfN + cc];
        __bf16 h = (__bf16)v;
        Whi[lidx] = h;
        Wlo[lidx] = (__bf16)(v - (float)h);
        return;
    }
    // int64 detection: odd words of first 64 edges are high halves (always 0
    // for int64 since idx<1e5); random src indices for int32.
    unsigned int wv = w[1 + 2 * (threadIdx.x & 63)];
    int f = __any(wv != 0);            // 1 => int32, 0 => int64
    int e = (blockIdx.x - wpB) * 256 + threadIdx.x;
    if (e >= E) return;
    int s = (int)(f ? w[e] : w[2 * (size_t)e]);
    int d = (int)(f ? w[E + e] : w[2 * ((size_t)E + e)]);
    idx32[e] = s;
    idx32[E + e] = d;
    rank[e] = atomicAdd(&deg[d], 1);
}

// ---------------- scans ----------------
__global__ __launch_bounds__(256) void k_scan1(const int* __restrict__ deg,
                                               int* __restrict__ offs,
                                               int* __restrict__ bsum, int n) {
    __shared__ int s[256];
    int t = threadIdx.x;
    int i = blockIdx.x * 256 + t;
    int v = (i < n) ? deg[i] : 0;
    s[t] = v;
    __syncthreads();
    for (int off = 1; off < 256; off <<= 1) {
        int add = (t >= off) ? s[t - off] : 0;
        __syncthreads();
        s[t] += add;
        __syncthreads();
    }
    if (i < n) offs[i] = s[t] - v;
    if (t == 255) bsum[blockIdx.x] = s[255];
}

__global__ __launch_bounds__(256) void k_scan2(int* __restrict__ bsum, int nb) {
    __shared__ int s[256];
    __shared__ int carry;
    int t = threadIdx.x;
    if (t == 0) carry = 0;
    __syncthreads();
    for (int base = 0; base < nb; base += 256) {
        int i = base + t;
        int v = (i < nb) ? bsum[i] : 0;
        s[t] = v;
        __syncthreads();
        for (int off = 1; off < 256; off <<= 1) {
            int add = (t >= off) ? s[t - off] : 0;
            __syncthreads();
            s[t] += add;
            __syncthreads();
        }
        if (i < nb) bsum[i] = s[t] - v + carry;
        __syncthreads();
        if (t == 0) carry += s[255];
        __syncthreads();
    }
}

__global__ void k_scan3(int* __restrict__ offs, const int* __restrict__ bsum,
                        int n, int E) {
    int i = blockIdx.x * blockDim.x + threadIdx.x;
    if (i < n) offs[i] += bsum[i >> 8];
    if (i == 0) offs[n] = E;
}

// ---------------- bf16x3 MFMA GEMM body (device) ------------
template <int K, int NCS, int SPLITC>
__device__ void mfma_body(const float* __restrict__ A,
                          const __bf16* __restrict__ Wthi,
                          const __bf16* __restrict__ Wtlo,
                          __bf16* __restrict__ Cl, float* __restrict__ Cr,
                          int M, int bid) {
    const int lane = threadIdx.x & 63;
    const int wave = threadIdx.x >> 6;
    const int row0 = bid * 128 + wave * 32;
    const int rlo = lane & 15;
    const int rhi = lane >> 4;            // 0..3

    f32x4 acc[NCS][2][2] = {};

    for (int k0 = 0; k0 < K; k0 += 32) {
        bf16x8 ahi[2], alo[2];
        #pragma unroll
        for (int wr = 0; wr < 2; ++wr) {
            int row = row0 + wr * 16 + rlo;
            row = row < M ? row : M - 1;
            const float* ap = A + (size_t)row * K + k0 + rhi * 8;
            float4 v0 = *(const float4*)ap;
            float4 v1 = *(const float4*)(ap + 4);
            float vv[8] = {v0.x, v0.y, v0.z, v0.w, v1.x, v1.y, v1.z, v1.w};
            #pragma unroll
            for (int i = 0; i < 8; ++i) {
                __bf16 h = (__bf16)vv[i];
                ahi[wr][i] = h;
                alo[wr][i] = (__bf16)(vv[i] - (float)h);
            }
        }
        #pragma unroll
        for (int cs = 0; cs < NCS; ++cs) {
            #pragma unroll
            for (int cf = 0; cf < 2; ++cf) {
                int c = cs * 32 + cf * 16 + rlo;
                size_t boff = (size_t)c * K + k0 + rhi * 8;
                bf16x8 bhi = *(const bf16x8*)(Wthi + boff);
                bf16x8 blo = *(const bf16x8*)(Wtlo + boff);
                #pragma unroll
                for (int wr = 0; wr < 2; ++wr) {
                    f32x4 a = acc[cs][wr][cf];
                    a = __builtin_amdgcn_mfma_f32_16x16x32_bf16(ahi[wr], bhi, a, 0, 0, 0);
                    a = __builtin_amdgcn_mfma_f32_16x16x32_bf16(ahi[wr], blo, a, 0, 0, 0);
                    a = __builtin_amdgcn_mfma_f32_16x16x32_bf16(alo[wr], bhi, a, 0, 0, 0);
                    acc[cs][wr][cf] = a;
                }
            }
        }
    }

    #pragma unroll
    for (int cs = 0; cs < NCS; ++cs)
        #pragma unroll
        for (int cf = 0; cf < 2; ++cf) {
            int c = cs * 32 + cf * 16 + rlo;
            #pragma unroll
            for (int wr = 0; wr < 2; ++wr)
                #pragma unroll
                for (int r = 0; r < 4; ++r) {
                    int row = row0 + wr * 16 + rhi * 4 + r;
                    if (row < M) {
                        float val = acc[cs][wr][cf][r];
                        if (c < SPLITC)
                            Cl[(size_t)row * SPLITC + c] = (__bf16)val;
                        else
                            Cr[(size_t)row * (NCS * 32 - SPLITC) + (c - SPLITC)] = val;
                    }
                }
        }
}

// plain GEMM kernel (layer 2)
template <int K, int NCS, int SPLITC>
__global__ __launch_bounds__(256) void k_mfma(const float* __restrict__ A,
                                              const __bf16* __restrict__ Wthi,
                                              const __bf16* __restrict__ Wtlo,
                                              __bf16* __restrict__ Cl,
                                              float* __restrict__ Cr, int M) {
    mfma_body<K, NCS, SPLITC>(A, Wthi, Wtlo, Cl, Cr, M, blockIdx.x);
}

// fused layer-1 GEMM (first) + CSR scatter (R5 ordering — measured best)
template <int K, int NCS, int SPLITC>
__global__ __launch_bounds__(256) void k_mfma_bin(const float* __restrict__ A,
                                                  const __bf16* __restrict__ Wthi,
                                                  const __bf16* __restrict__ Wtlo,
                                                  __bf16* __restrict__ Cl,
                                                  float* __restrict__ Cr, int M,
                                                  int gemmBlocks,
                                                  const int* __restrict__ idx32,
                                                  const int* __restrict__ rank,
                                                  const int* __restrict__ offs,
                                                  int* __restrict__ csr, int E) {
    if ((int)blockIdx.x >= gemmBlocks) {
        int e = (blockIdx.x - gemmBlocks) * 256 + threadIdx.x;
        if (e < E) {
            int d = idx32[E + e];
            csr[offs[d] + rank[e]] = idx32[e];
        }
        return;
    }
    mfma_body<K, NCS, SPLITC>(A, Wthi, Wtlo, Cl, Cr, M, blockIdx.x);
}

// ---------------- fused gather(bf16) + mean + lin_r + BN + ReLU ------------
// one wave per node; 16 lanes per row => 4 rows per wave-load (uint4/uint2),
// intra-wave combine via shfl_xor(16/32).
template <int LOGF>
__global__ __launch_bounds__(256) void k_agg(const __bf16* __restrict__ xl,
                                             const float* __restrict__ lin,
                                             const int* __restrict__ csr,
                                             const int* __restrict__ offs,
                                             const float* __restrict__ b,
                                             const float* __restrict__ g,
                                             const float* __restrict__ be,
                                             const float* __restrict__ m,
                                             const float* __restrict__ v,
                                             float* __restrict__ out, int N) {
    constexpr int F = 1 << LOGF;
    constexpr int NW = (F == 128) ? 8 : 4;   // floats accumulated per lane
    int node = blockIdx.x * 4 + (threadIdx.x >> 6);
    if (node >= N) return;
    int lane = threadIdx.x & 63;
    int sub = lane >> 4;                  // row-group 0..3
    int col = lane & 15;                  // feature-group
    int beg = offs[node], end = offs[node + 1];
    float inv = 1.0f / fmaxf((float)(end - beg), 1.0f);

    float sx[NW];
    #pragma unroll
    for (int j = 0; j < NW; ++j) sx[j] = 0.f;

    int e = beg;
    while (e < end) {
        int bl = min(64, end - e);
        int myidx = (lane < bl) ? csr[e + lane] : 0;
        int u = 0;
        // 8 rows per iteration (two 4-row wave-loads in flight)
        for (; u + 8 <= bl; u += 8) {
            int s0 = __shfl(myidx, u + sub, 64);
            int s1 = __shfl(myidx, u + 4 + sub, 64);
            if constexpr (F == 128) {
                uint4 t0 = *(const uint4*)((const char*)xl + (size_t)s0 * 256 + col * 16);
                uint4 t1 = *(const uint4*)((const char*)xl + (size_t)s1 * 256 + col * 16);
                unsigned int w0[4] = {t0.x, t0.y, t0.z, t0.w};
                unsigned int w1[4] = {t1.x, t1.y, t1.z, t1.w};
                #pragma unroll
                for (int i = 0; i < 4; ++i) {
                    sx[2 * i]     += __uint_as_float(w0[i] << 16) + __uint_as_float(w1[i] << 16);
                    sx[2 * i + 1] += __uint_as_float(w0[i] & 0xffff0000u) + __uint_as_float(w1[i] & 0xffff0000u);
                }
            } else {
                uint2 t0 = *(const uint2*)((const char*)xl + (size_t)s0 * 128 + col * 8);
                uint2 t1 = *(const uint2*)((const char*)xl + (size_t)s1 * 128 + col * 8);
                unsigned int w0[2] = {t0.x, t0.y};
                unsigned int w1[2] = {t1.x, t1.y};
                #pragma unroll
                for (int i = 0; i < 2; ++i) {
                    sx[2 * i]     += __uint_as_float(w0[i] << 16) + __uint_as_float(w1[i] << 16);
                    sx[2 * i + 1] += __uint_as_float(w0[i] & 0xffff0000u) + __uint_as_float(w1[i] & 0xffff0000u);
                }
            }
        }
        // 4-row step
        for (; u + 4 <= bl; u += 4) {
            int s0 = __shfl(myidx, u + sub, 64);
            if constexpr (F == 128) {
                uint4 t0 = *(const uint4*)((const char*)xl + (size_t)s0 * 256 + col * 16);
                unsigned int w0[4] = {t0.x, t0.y, t0.z, t0.w};
                #pragma unroll
                for (int i = 0; i < 4; ++i) {
                    sx[2 * i]     += __uint_as_float(w0[i] << 16);
                    sx[2 * i + 1] += __uint_as_float(w0[i] & 0xffff0000u);
                }
            } else {
                uint2 t0 = *(const uint2*)((const char*)xl + (size_t)s0 * 128 + col * 8);
                unsigned int w0[2] = {t0.x, t0.y};
                #pragma unroll
                for (int i = 0; i < 2; ++i) {
                    sx[2 * i]     += __uint_as_float(w0[i] << 16);
                    sx[2 * i + 1] += __uint_as_float(w0[i] & 0xffff0000u);
                }
            }
        }
        // tail 1..3 rows, predicated
        if (u < bl) {
            int rr = u + sub;
            int s0 = __shfl(myidx, rr < bl ? rr : u, 64);
            bool ok = rr < bl;
            if constexpr (F == 128) {
                uint4 t0 = *(const uint4*)((const char*)xl + (size_t)s0 * 256 + col * 16);
                unsigned int w0[4] = {t0.x, t0.y, t0.z, t0.w};
                #pragma unroll
                for (int i = 0; i < 4; ++i) {
                    sx[2 * i]     += ok ? __uint_as_float(w0[i] << 16) : 0.f;
                    sx[2 * i + 1] += ok ? __uint_as_float(w0[i] & 0xffff0000u) : 0.f;
                }
            } else {
                uint2 t0 = *(const uint2*)((const char*)xl + (size_t)s0 * 128 + col * 8);
                unsigned int w0[2] = {t0.x, t0.y};
                #pragma unroll
                for (int i = 0; i < 2; ++i) {
                    sx[2 * i]     += ok ? __uint_as_float(w0[i] << 16) : 0.f;
                    sx[2 * i + 1] += ok ? __uint_as_float(w0[i] & 0xffff0000u) : 0.f;
                }
            }
        }
        e += bl;
    }

    // combine the 4 row-groups
    #pragma unroll
    for (int j = 0; j < NW; ++j) {
        sx[j] += __shfl_xor(sx[j], 16, 64);
        sx[j] += __shfl_xor(sx[j], 32, 64);
    }

    // epilogue on sub==0 lanes (16 lanes cover the full row)
    if (sub == 0) {
        #pragma unroll
        for (int j = 0; j < NW; ++j) {
            int f = col * NW + j;
            size_t o = (size_t)node * F + f;
            float y = ((sx[j] * inv + b[f] + lin[o]) - m[f]) *
                      (g[f] * rsqrtf(v[f] + BN_EPS)) + be[f];
            out[o] = fmaxf(y, 0.f);
        }
    }
}

// ---------------- head: out[M,10] = h2[M,64] @ Wh[64,10] + bh --------------
__global__ __launch_bounds__(256) void k_head(const float* __restrict__ h2,
                                              const float* __restrict__ Wh,
                                              const float* __restrict__ bh,
                                              float* __restrict__ out, int M) {
    __shared__ float sW[64 * 10];
    __shared__ float sb[10];
    for (int i = threadIdx.x; i < 640; i += 256) sW[i] = Wh[i];
    if (threadIdx.x < 10) sb[threadIdx.x] = bh[threadIdx.x];
    __syncthreads();
    int n = blockIdx.x * blockDim.x + threadIdx.x;
    if (n >= M) return;
    float acc[10];
    #pragma unroll
    for (int c = 0; c < 10; ++c) acc[c] = sb[c];
    const float* hr = h2 + (size_t)n * 64;
    #pragma unroll
    for (int k = 0; k < 64; ++k) {
        float hv = hr[k];
        #pragma unroll
        for (int c = 0; c < 10; ++c) acc[c] = fmaf(hv, sW[k * 10 + c], acc[c]);
    }
    #pragma unroll
    for (int c = 0; c < 10; ++c) out[(size_t)n * 10 + c] = acc[c];
}

// ---------------------------------------------------------------------------
static inline size_t align256(size_t x) { return (x + 255) & ~(size_t)255; }

extern "C" void kernel_launch(void* const* d_in, const int* in_sizes, int n_in,
                              void* d_out, int out_size, void* d_ws, size_t ws_size,
                              hipStream_t stream) {
    const float* x   = (const float*)d_in[0];
    const void*  ei  = d_in[1];
    const float* W1l = (const float*)d_in[2];
    const float* b1l = (const float*)d_in[3];
    const float* W1r = (const float*)d_in[4];
    const float* g1  = (const float*)d_in[5];
    const float* be1 = (const float*)d_in[6];
    const float* m1  = (const float*)d_in[7];
    const float* v1  = (const float*)d_in[8];
    const float* W2l = (const float*)d_in[9];
    const float* b2l = (const float*)d_in[10];
    const float* W2r = (const float*)d_in[11];
    const float* g2  = (const float*)d_in[12];
    const float* be2 = (const float*)d_in[13];
    const float* m2  = (const float*)d_in[14];
    const float* v2  = (const float*)d_in[15];
    const float* Wh  = (const float*)d_in[16];
    const float* bh  = (const float*)d_in[17];
    float* out = (float*)d_out;

    const int N = N_NODES;
    const int E = in_sizes[1] / 2;
    const int NB = (N + 255) / 256;

    // -------- workspace layout --------
    char* p = (char*)d_ws;
    int* idx32 = (int*)p;  p += align256((size_t)2 * E * 4);
    int* rank  = (int*)p;  p += align256((size_t)E * 4);
    int* csr   = (int*)p;  p += align256((size_t)E * 4);
    int* offs  = (int*)p;  p += align256((size_t)(N + 1) * 4);
    int* deg   = (int*)p;  p += align256((size_t)N * 4);
    int* bsum  = (int*)p;  p += 4096;
    __bf16* Wt1hi = (__bf16*)p; p += align256((size_t)256 * 128 * 2);
    __bf16* Wt1lo = (__bf16*)p; p += align256((size_t)256 * 128 * 2);
    __bf16* Wt2hi = (__bf16*)p; p += align256((size_t)128 * 128 * 2);
    __bf16* Wt2lo = (__bf16*)p; p += align256((size_t)128 * 128 * 2);
    __bf16* xl = (__bf16*)p; p += align256((size_t)N * 128 * 2);
    float* xr  = (float*)p;  p += (size_t)N * 128 * 4;
    float* h   = (float*)p;  p += (size_t)N * 128 * 4;
    // layer-2 reuse
    __bf16* t2l = xl;                    // [N,64] bf16
    float* t2r  = xr;                    // [N,64] f32
    float* h2   = h;                     // [N,64] f32 (h dead after mfma2)

    dim3 blk(256);

    // -------- fused weight-prep + edge prep --------
    const int WPB = (2 * 128 * 128 + 2 * 64 * 128 + 255) / 256;   // 192
    int prepB = (E + 255) / 256;
    hipMemsetAsync(deg, 0, (size_t)N * 4, stream);
    k_prep<<<dim3(WPB + prepB), blk, 0, stream>>>(
        (const unsigned int*)ei, E, idx32, rank, deg, WPB,
        W1l, W1r, W2l, W2r, Wt1hi, Wt1lo, Wt2hi, Wt2lo);

    // -------- scans --------
    k_scan1<<<dim3(NB), blk, 0, stream>>>(deg, offs, bsum, N);
    k_scan2<<<dim3(1), blk, 0, stream>>>(bsum, NB);
    k_scan3<<<dim3(NB), blk, 0, stream>>>(offs, bsum, N, E);

    // -------- layer-1 GEMM (first) co-scheduled with CSR scatter --------
    int gemmBlocks = (N + 127) / 128;
    int binBlocks = (E + 255) / 256;
    k_mfma_bin<128, 8, 128><<<dim3(gemmBlocks + binBlocks), blk, 0, stream>>>(
        x, Wt1hi, Wt1lo, xl, xr, N, gemmBlocks, idx32, rank, offs, csr, E);

    // -------- layer 1 aggregate --------
    k_agg<7><<<dim3((N + 3) / 4), blk, 0, stream>>>(
        xl, xr, csr, offs, b1l, g1, be1, m1, v1, h, N);

    // -------- layer 2 --------
    k_mfma<128, 4, 64><<<dim3(gemmBlocks), blk, 0, stream>>>(h, Wt2hi, Wt2lo, t2l, t2r, N);
    k_agg<6><<<dim3((N + 3) / 4), blk, 0, stream>>>(
        t2l, t2r, csr, offs, b2l, g2, be2, m2, v2, h2, N);

    // -------- head --------
    k_head<<<dim3((N + 255) / 256), blk, 0, stream>>>(h2, Wh, bh, out, N);
}